// Round 7
// baseline (265.941 us; speedup 1.0000x reference)
//
#include <hip/hip_runtime.h>

#define L_SEQ   4096
#define D_MODEL 512
#define NSEQ    2048   // BATCH * D_MODEL
#define CH      128    // chunk length
#define NC      32     // chunks

// workspace float offsets
#define OFF_P    0        // P = A^128, [i][j] row-major, 4096
#define OFF_W1T  4096     // W1T[r][i] = (A^{127-r} b)[i], 128x64
#define OFF_WOUT 12288    // Wout[i][r] = (c^T A^{r+1})[i], 64x128
#define OFF_KLOC 20480    // KlocZ[0..127]=0, KlocZ[128+m]=c^T A^m b, 256
#define OFF_GX   20736    // gx[c][i][s]: proj writes G^T, scan overwrites X^T

#define BC(v, j) __int_as_float(__builtin_amdgcn_readlane(__float_as_int(v), (j)))

// acc[8][4] += {a0,a1} (8 rows) * b (4 cols)
#define FMAC84(acc, a0, a1, b)                                                \
  acc[0][0]+=a0.x*b.x; acc[0][1]+=a0.x*b.y; acc[0][2]+=a0.x*b.z; acc[0][3]+=a0.x*b.w; \
  acc[1][0]+=a0.y*b.x; acc[1][1]+=a0.y*b.y; acc[1][2]+=a0.y*b.z; acc[1][3]+=a0.y*b.w; \
  acc[2][0]+=a0.z*b.x; acc[2][1]+=a0.z*b.y; acc[2][2]+=a0.z*b.z; acc[2][3]+=a0.z*b.w; \
  acc[3][0]+=a0.w*b.x; acc[3][1]+=a0.w*b.y; acc[3][2]+=a0.w*b.z; acc[3][3]+=a0.w*b.w; \
  acc[4][0]+=a1.x*b.x; acc[4][1]+=a1.x*b.y; acc[4][2]+=a1.x*b.z; acc[4][3]+=a1.x*b.w; \
  acc[5][0]+=a1.y*b.x; acc[5][1]+=a1.y*b.y; acc[5][2]+=a1.y*b.z; acc[5][3]+=a1.y*b.w; \
  acc[6][0]+=a1.z*b.x; acc[6][1]+=a1.z*b.y; acc[6][2]+=a1.z*b.z; acc[6][3]+=a1.z*b.w; \
  acc[7][0]+=a1.w*b.x; acc[7][1]+=a1.w*b.y; acc[7][2]+=a1.w*b.z; acc[7][3]+=a1.w*b.w;

// ===========================================================================
// k_prep (1 block): log-doubling construction — no sequential 64-step chains.
//   Vt[m][k]  = (A^m b)[k],        m = 0..127
//   Wtt[r][k] = (c^T A^{r+1})[k],  r = 0..127
// Per level j (0..5): waves 0/1 double V/W using Q_j (uniform b128 broadcast
// reads of Vt/Wtt rows, Q row/col cached in VGPRs), waves 2/3 square
// Q_j -> Q_{j+1} (8x4 micro on Q + QT). Level 6 (A^64) uses all 4 waves.
// Final: waves 2/3 square A^64 -> P while waves 0/1 write the output tables.
// ===========================================================================
__global__ __launch_bounds__(256) void k_prep(
    const float* __restrict__ A, const float* __restrict__ B,
    const float* __restrict__ C, float* __restrict__ ws) {
  __shared__ float Q0[64][68], Q0T[64][68], Q1[64][68], Q1T[64][68];
  __shared__ float Vt[128][66];   // Vt[m][k]
  __shared__ float Wtt[128][66];  // Wtt[r][k]
  __shared__ __align__(16) float Cs[64], Bsh[64];

  const int tid = threadIdx.x;
  const int lane = tid & 63, wv = tid >> 6;

  if (tid < 64) { Cs[tid] = C[tid]; Bsh[tid] = B[tid]; }
  for (int e = tid; e < 4096; e += 256) {
    const int i = e >> 6, j = e & 63;
    const float a = A[e];
    Q0[i][j] = a;
    Q0T[j][i] = a;
  }
  __syncthreads();

  // init: Vt[0][k] = b[k];  Wtt[0][k] = (c^T A)[k] = sum_i c[i] A[i][k]
  if (tid < 64) {
    float acc = 0.f;
#pragma unroll
    for (int i4 = 0; i4 < 16; ++i4) {
      const float4 q = *(const float4*)&Q0T[tid][i4 * 4];
      const float4 cc = *(const float4*)&Cs[i4 * 4];
      acc += q.x * cc.x + q.y * cc.y + q.z * cc.z + q.w * cc.w;
    }
    Wtt[0][tid] = acc;
  } else if (tid < 128) {
    Vt[0][tid - 64] = Bsh[tid - 64];
  }
  __syncthreads();

  // ---- levels 0..5: doubling (waves 0,1) || squaring (waves 2,3) ----
  for (int j = 0; j < 6; ++j) {
    const int ncols = 1 << j;
    float (*Qc)[68]  = (j & 1) ? Q1 : Q0;
    float (*QcT)[68] = (j & 1) ? Q1T : Q0T;
    float (*Qn)[68]  = (j & 1) ? Q0 : Q1;
    float (*QnT)[68] = (j & 1) ? Q0T : Q1T;
    if (wv < 2) {
      float qr[64];
      float (*Qsrc)[68] = (wv == 0) ? Qc : QcT;  // V: Q rows; W: Q cols
      float (*T)[66]    = (wv == 0) ? Vt : Wtt;
#pragma unroll
      for (int k4 = 0; k4 < 16; ++k4) {
        const float4 v = *(const float4*)&Qsrc[lane][k4 * 4];
        qr[k4*4] = v.x; qr[k4*4+1] = v.y; qr[k4*4+2] = v.z; qr[k4*4+3] = v.w;
      }
      for (int m = 0; m < ncols; ++m) {
        float a0 = 0.f, a1 = 0.f, a2 = 0.f, a3 = 0.f;
#pragma unroll
        for (int k4 = 0; k4 < 16; ++k4) {
          const float4 v = *(const float4*)&T[m][k4 * 4];  // uniform: broadcast
          a0 += qr[k4*4]     * v.x;
          a1 += qr[k4*4 + 1] * v.y;
          a2 += qr[k4*4 + 2] * v.z;
          a3 += qr[k4*4 + 3] * v.w;
        }
        T[ncols + m][lane] = (a0 + a1) + (a2 + a3);
      }
    } else {
      const int t = tid - 128;
      const int rt = (t >> 4) * 8, ct = (t & 15) * 4;
      float acc[8][4] = {{0.f}};
#pragma unroll 8
      for (int k = 0; k < 64; ++k) {
        const float4 a0 = *(const float4*)&QcT[k][rt];
        const float4 a1 = *(const float4*)&QcT[k][rt + 4];
        const float4 b  = *(const float4*)&Qc[k][ct];
        FMAC84(acc, a0, a1, b);
      }
#pragma unroll
      for (int r = 0; r < 8; ++r) {
        float4 v; v.x = acc[r][0]; v.y = acc[r][1]; v.z = acc[r][2]; v.w = acc[r][3];
        *(float4*)&Qn[rt + r][ct] = v;
      }
#pragma unroll
      for (int cc = 0; cc < 4; ++cc) {
        float4 v0, v1;
        v0.x = acc[0][cc]; v0.y = acc[1][cc]; v0.z = acc[2][cc]; v0.w = acc[3][cc];
        v1.x = acc[4][cc]; v1.y = acc[5][cc]; v1.z = acc[6][cc]; v1.w = acc[7][cc];
        *(float4*)&QnT[ct + cc][rt] = v0;
        *(float4*)&QnT[ct + cc][rt + 4] = v1;
      }
    }
    __syncthreads();
  }

  // ---- level 6: cols 64..127 using Q0 = A^64; all 4 waves ----
  {
    float qr[64];
    float (*Qsrc)[68] = (wv < 2) ? Q0 : Q0T;
    float (*T)[66]    = (wv < 2) ? Vt : Wtt;
    const int half = (wv & 1) * 32;
#pragma unroll
    for (int k4 = 0; k4 < 16; ++k4) {
      const float4 v = *(const float4*)&Qsrc[lane][k4 * 4];
      qr[k4*4] = v.x; qr[k4*4+1] = v.y; qr[k4*4+2] = v.z; qr[k4*4+3] = v.w;
    }
    for (int m = half; m < half + 32; ++m) {
      float a0 = 0.f, a1 = 0.f, a2 = 0.f, a3 = 0.f;
#pragma unroll
      for (int k4 = 0; k4 < 16; ++k4) {
        const float4 v = *(const float4*)&T[m][k4 * 4];
        a0 += qr[k4*4]     * v.x;
        a1 += qr[k4*4 + 1] * v.y;
        a2 += qr[k4*4 + 2] * v.z;
        a3 += qr[k4*4 + 3] * v.w;
      }
      T[64 + m][lane] = (a0 + a1) + (a2 + a3);
    }
    __syncthreads();
  }

  // ---- final: waves 2,3 square A^64 -> P (Q1); waves 0,1 write tables ----
  if (wv >= 2) {
    const int t = tid - 128;
    const int rt = (t >> 4) * 8, ct = (t & 15) * 4;
    float acc[8][4] = {{0.f}};
#pragma unroll 8
    for (int k = 0; k < 64; ++k) {
      const float4 a0 = *(const float4*)&Q0T[k][rt];
      const float4 a1 = *(const float4*)&Q0T[k][rt + 4];
      const float4 b  = *(const float4*)&Q0[k][ct];
      FMAC84(acc, a0, a1, b);
    }
#pragma unroll
    for (int r = 0; r < 8; ++r) {
      float4 v; v.x = acc[r][0]; v.y = acc[r][1]; v.z = acc[r][2]; v.w = acc[r][3];
      *(float4*)&Q1[rt + r][ct] = v;
    }
  } else {
    float* W1Tg = ws + OFF_W1T;
    float* Wg = ws + OFF_WOUT;
    float* Kz = ws + OFF_KLOC;
    for (int e = tid; e < 8192; e += 128) {       // W1T[r][i] = Vt[127-r][i]
      W1Tg[e] = Vt[127 - (e >> 6)][e & 63];
    }
    for (int e = tid; e < 8192; e += 128) {       // Wout[i][r] = Wtt[r][i]
      Wg[e] = Wtt[e & 127][e >> 7];
    }
    {
      const int m = tid;                          // 0..127
      Kz[m] = 0.f;                                // guard zeros
      float acc = 0.f;
      if (m == 0) {
#pragma unroll
        for (int i4 = 0; i4 < 16; ++i4) {
          const float4 cc = *(const float4*)&Cs[i4 * 4];
          const float4 bb = *(const float4*)&Bsh[i4 * 4];
          acc += cc.x * bb.x + cc.y * bb.y + cc.z * bb.z + cc.w * bb.w;
        }
      } else {
#pragma unroll
        for (int i4 = 0; i4 < 16; ++i4) {
          const float4 w = *(const float4*)&Wtt[m - 1][i4 * 4];
          const float4 bb = *(const float4*)&Bsh[i4 * 4];
          acc += w.x * bb.x + w.y * bb.y + w.z * bb.z + w.w * bb.w;
        }
      }
      Kz[128 + m] = acc;
    }
  }
  __syncthreads();

  float* Pg = ws + OFF_P;
  for (int e = tid; e < 4096; e += 256) Pg[e] = Q1[e >> 6][e & 63];
}

// ===========================================================================
// k_proj: G^T[c][i][s] = sum_r W1T[r][i] * u[c*128+r][s]
// 64 i x 64 s per block, K=128. A-operand direct from L1-resident W1T;
// LDS serves only the u tile. 128 threads, micro 8x4.
// ===========================================================================
__global__ __launch_bounds__(128) void k_proj(
    const float* __restrict__ u, const float* __restrict__ wsr,
    float* __restrict__ gx) {
  __shared__ float Us[64][64];

  const int st = blockIdx.x;     // 0..31 (64 seqs)
  const int c  = blockIdx.y;     // 0..31
  const int tid = threadIdx.x;
  const int s0 = st * 64;
  const int bi = s0 >> 9, d0 = s0 & 511;
  const float* W1Tg = wsr + OFF_W1T;
  const float* ub = u + ((size_t)bi * L_SEQ + c * CH) * D_MODEL + d0;
  const int ig = tid >> 4;
  const int sg = tid & 15;

  float acc[8][4] = {{0.f}};
  for (int h = 0; h < 2; ++h) {
    __syncthreads();
#pragma unroll
    for (int n = 0; n < 8; ++n) {
      const int e = tid + 128 * n;
      const int rr = e >> 4, s4 = (e & 15) * 4;
      *(((float4*)Us) + e) =
          *(const float4*)(ub + (size_t)(h * 64 + rr) * D_MODEL + s4);
    }
    __syncthreads();
#pragma unroll 4
    for (int rr = 0; rr < 64; ++rr) {
      const float* wr = W1Tg + (size_t)(h * 64 + rr) * 64 + ig * 8;
      const float4 a0 = *(const float4*)wr;
      const float4 a1 = *(const float4*)(wr + 4);
      const float4 b  = *(const float4*)&Us[rr][sg * 4];
      FMAC84(acc, a0, a1, b);
    }
  }

  float* gb = gx + (size_t)c * 64 * NSEQ + s0 + sg * 4;
#pragma unroll
  for (int j = 0; j < 8; ++j) {
    float4 v; v.x = acc[j][0]; v.y = acc[j][1]; v.z = acc[j][2]; v.w = acc[j][3];
    *(float4*)(gb + (size_t)(ig * 8 + j) * NSEQ) = v;
  }
}

// ===========================================================================
// k_scan: x_{c+1} = P x_c + g_c; overwrites g[c] (layout [c][i][s]) with the
// pre-chunk state X^T[c][i][s] in place (blocks own disjoint s -> race-free).
// 256 threads = 4 seqs per block (wave = seq, lane = state), 512 blocks
// (2/CU for overlap). Triple-buffered coop g-prefetch issued 2 chunks early.
// ===========================================================================
__global__ __launch_bounds__(256) void k_scan(
    const float* __restrict__ wsr, float* __restrict__ gx) {
  __shared__ float gbuf[3][64][5];
  __shared__ float xbuf[64][5];
  const int tid = threadIdx.x;
  const int lane = tid & 63, wv = tid >> 6;
  const int s0 = blockIdx.x * 4;
  const int ci = tid >> 2, cj = tid & 3;

  float p[64];
#pragma unroll
  for (int j4 = 0; j4 < 16; ++j4) {
    const float4 v = *(const float4*)(wsr + OFF_P + lane * 64 + j4 * 4);
    p[j4*4] = v.x; p[j4*4+1] = v.y; p[j4*4+2] = v.z; p[j4*4+3] = v.w;
  }

  gbuf[0][ci][cj] = gx[(size_t)ci * NSEQ + s0 + cj];
  gbuf[1][ci][cj] = gx[(size_t)(64 + ci) * NSEQ + s0 + cj];

  float x = 0.f;
  for (int c = 0; c < NC; ++c) {
    xbuf[lane][wv] = x;
    __syncthreads();
    gx[(size_t)(c * 64 + ci) * NSEQ + s0 + cj] = xbuf[ci][cj];  // X^T[c]
    if (c + 2 < NC)
      gbuf[(c + 2) % 3][ci][cj] =
          gx[(size_t)((c + 2) * 64 + ci) * NSEQ + s0 + cj];
    const float g = gbuf[c % 3][lane][wv];
    float a0 = g, a1 = 0.f, a2 = 0.f, a3 = 0.f;
#pragma unroll
    for (int j = 0; j < 64; j += 4) {
      a0 += p[j]     * BC(x, j);
      a1 += p[j + 1] * BC(x, j + 1);
      a2 += p[j + 2] * BC(x, j + 2);
      a3 += p[j + 3] * BC(x, j + 3);
    }
    x = (a0 + a1) + (a2 + a3);
    __syncthreads();
  }
}

// ===========================================================================
// k_localout: y[c*128+r][s] = sum_{k<=r} Kloc[r-k] u[c*128+k][s]
//                           + sum_i Wout[i][r] X_c[i][s]
// 128 rows x 64 seqs per block, 256 threads, micro 8x4. A-operands direct
// from L1-resident KlocZ/Wout; LDS holds only the 64x64 B tile.
// ===========================================================================
__global__ __launch_bounds__(256) void k_localout(
    const float* __restrict__ u, const float* __restrict__ wsr,
    const float* __restrict__ gx, float* __restrict__ out) {
  __shared__ float Bs[64][64];

  const int st = blockIdx.x;
  const int c  = blockIdx.y;
  const int tid = threadIdx.x;
  const int s0 = st * 64;
  const int bi = s0 >> 9, d0 = s0 & 511;
  const int rg = tid >> 4;
  const int sq = tid & 15;
  const float* KlocZ = wsr + OFF_KLOC;
  const float* WoutG = wsr + OFF_WOUT;
  const float* ub = u + ((size_t)bi * L_SEQ + c * CH) * D_MODEL + d0;

  float acc[8][4] = {{0.f}};

  // ---- A1: k rows 0..63 ----
#pragma unroll
  for (int n = 0; n < 4; ++n) {
    const int e = tid + 256 * n;
    *(((float4*)Bs) + e) =
        *(const float4*)(ub + (size_t)(e >> 4) * D_MODEL + (e & 15) * 4);
  }
  __syncthreads();
  {
    const float* k0p = KlocZ + 128 + rg * 8;
#pragma unroll 4
    for (int kk = 0; kk < 64; ++kk) {
      float4 a0, a1;
      __builtin_memcpy(&a0, k0p - kk, 16);
      __builtin_memcpy(&a1, k0p - kk + 4, 16);
      const float4 b = *(const float4*)&Bs[kk][sq * 4];
      FMAC84(acc, a0, a1, b);
    }
  }
  __syncthreads();

  // ---- A2: k rows 64..127, only output rows >= 64 ----
#pragma unroll
  for (int n = 0; n < 4; ++n) {
    const int e = tid + 256 * n;
    *(((float4*)Bs) + e) =
        *(const float4*)(ub + (size_t)(64 + (e >> 4)) * D_MODEL + (e & 15) * 4);
  }
  __syncthreads();
  if (rg >= 8) {
    const float* k0p = KlocZ + 64 + rg * 8;
#pragma unroll 4
    for (int kk = 0; kk < 64; ++kk) {
      float4 a0, a1;
      __builtin_memcpy(&a0, k0p - kk, 16);
      __builtin_memcpy(&a1, k0p - kk + 4, 16);
      const float4 b = *(const float4*)&Bs[kk][sq * 4];
      FMAC84(acc, a0, a1, b);
    }
  }
  __syncthreads();

  // ---- B: Wout * X_c ----
#pragma unroll
  for (int n = 0; n < 4; ++n) {
    const int e = tid + 256 * n;
    *(((float4*)Bs) + e) = *(const float4*)(
        gx + (size_t)(c * 64 + (e >> 4)) * NSEQ + s0 + (e & 15) * 4);
  }
  __syncthreads();
  {
#pragma unroll 4
    for (int kk = 0; kk < 64; ++kk) {
      const float* wp = WoutG + kk * 128 + rg * 8;
      const float4 a0 = *(const float4*)wp;
      const float4 a1 = *(const float4*)(wp + 4);
      const float4 b = *(const float4*)&Bs[kk][sq * 4];
      FMAC84(acc, a0, a1, b);
    }
  }

  float* ob = out + ((size_t)bi * L_SEQ + c * CH) * D_MODEL + d0 + sq * 4;
#pragma unroll
  for (int j = 0; j < 8; ++j) {
    float4 v; v.x = acc[j][0]; v.y = acc[j][1]; v.z = acc[j][2]; v.w = acc[j][3];
    *(float4*)(ob + (size_t)(rg * 8 + j) * D_MODEL) = v;
  }
}

extern "C" void kernel_launch(void* const* d_in, const int* in_sizes, int n_in,
                              void* d_out, int out_size, void* d_ws,
                              size_t ws_size, hipStream_t stream) {
  const float* u = (const float*)d_in[0];   // (4, 4096, 512)
  const float* A = (const float*)d_in[1];   // (64, 64)
  const float* B = (const float*)d_in[2];   // (64, 1)
  const float* C = (const float*)d_in[3];   // (1, 64)
  float* out = (float*)d_out;
  float* ws = (float*)d_ws;                 // needs ~16.9 MB
  float* gx = ws + OFF_GX;

  k_prep<<<1, 256, 0, stream>>>(A, B, C, ws);
  k_proj<<<dim3(32, 32), 128, 0, stream>>>(u, ws, gx);
  k_scan<<<512, 256, 0, stream>>>(ws, gx);
  k_localout<<<dim3(32, 32), 256, 0, stream>>>(u, ws, gx, out);
}